// Round 6
// baseline (1169.855 us; speedup 1.0000x reference)
//
#include <hip/hip_runtime.h>
#include <hip/hip_fp16.h>

namespace {

constexpr int B = 4;
constexpr int N = 2048;
constexpr int E = 1024;
constexpr int H = 16;
constexpr int D = 64;
constexpr int M = B * N;  // 8192

typedef __attribute__((ext_vector_type(8))) short bf16x8;
typedef __attribute__((ext_vector_type(8))) _Float16 f16x8;
typedef __attribute__((ext_vector_type(4))) _Float16 f16x4;
typedef __attribute__((ext_vector_type(4))) float f32x4;

__device__ inline ushort bf16_rne(float f) {
  unsigned u = __float_as_uint(f);
  return (ushort)((u + 0x7FFFu + ((u >> 16) & 1u)) >> 16);
}
// fp32 -> hi (truncated bf16) + lo (rne bf16 of remainder); hi+lo ~ 17-bit mantissa
__device__ inline void split2(float f, ushort& hi, ushort& lo) {
  unsigned u = __float_as_uint(f);
  hi = (ushort)(u >> 16);
  lo = bf16_rne(f - __uint_as_float(u & 0xFFFF0000u));
}

// ---------------------------------------------------------------------------
// Elementwise fp32 -> (hi, lo) bf16 split
// ---------------------------------------------------------------------------
__global__ __launch_bounds__(256) void split_kernel(
    const float* __restrict__ in, ushort* __restrict__ hi,
    ushort* __restrict__ lo, int n4) {
  int i = blockIdx.x * blockDim.x + threadIdx.x;
  const int stride = gridDim.x * blockDim.x;
  for (; i < n4; i += stride) {
    const float4 f = ((const float4*)in)[i];
    ushort4 h, l;
    split2(f.x, h.x, l.x);
    split2(f.y, h.y, l.y);
    split2(f.z, h.z, l.z);
    split2(f.w, h.w, l.w);
    ((ushort4*)hi)[i] = h;
    ((ushort4*)lo)[i] = l;
  }
}

// ---------------------------------------------------------------------------
// bf16x3 MFMA GEMM. Tile 128x128, BK=32, 4 waves.
// MODE 0 epilogue: col = h*192 + d*3 + s ->
//   s==0: Q *(1/8) split -> Qh/Ql  [B,H,N,D] bf16
//   s==1: K split        -> Kh/Kl  [B,H,N,D] bf16
//   s==2: V -> Vtb [B,H,kt=N/64][d=64][64] fp16 tile-blocked transpose:
//          8B stores at 128B row stride (kills the stride-N write amp).
// MODE 1 epilogue: out[m][col] = acc + bias (fp32)
// ---------------------------------------------------------------------------
template <int MODE>
__global__ __launch_bounds__(256) void gemm_x3(
    const ushort* __restrict__ Ahg, const ushort* __restrict__ Alg,
    const ushort* __restrict__ Bhg, const ushort* __restrict__ Blg,
    const float* __restrict__ bias, ushort* __restrict__ qh,
    ushort* __restrict__ ql, ushort* __restrict__ kh, ushort* __restrict__ kl,
    ushort* __restrict__ vt, float* __restrict__ outp) {
  __shared__ ushort LAh[4096], LAl[4096], LBh[4096], LBl[4096];
  const int tid = threadIdx.x;
  const int l = tid & 63, wid = tid >> 6;
  const int wr = wid >> 1, wc = wid & 1;
  const int lr = l & 15, kg = l >> 4;
  const int m0 = blockIdx.x * 128, n0 = blockIdx.y * 128;

  f32x4 acc[4][4];
#pragma unroll
  for (int i = 0; i < 4; ++i)
#pragma unroll
    for (int j = 0; j < 4; ++j) acc[i][j] = (f32x4){0.f, 0.f, 0.f, 0.f};

  for (int k0 = 0; k0 < E; k0 += 32) {
    const ushort* gAh = Ahg + (size_t)m0 * E + k0;
    const ushort* gAl = Alg + (size_t)m0 * E + k0;
    const ushort* gBh = Bhg + (size_t)n0 * E + k0;
    const ushort* gBl = Blg + (size_t)n0 * E + k0;
    __syncthreads();
    auto stage = [&](const ushort* gp, ushort* lp, int half) {
      const int c = half * 256 + tid;
      __builtin_amdgcn_global_load_lds(
          (__attribute__((address_space(1))) void*)(gp + (size_t)(c >> 2) * E +
                                                    (c & 3) * 8),
          (__attribute__((address_space(3))) void*)(lp +
                                                    (half * 256 + (tid & ~63)) * 8),
          16, 0, 0);
    };
    stage(gAh, LAh, 0); stage(gAh, LAh, 1);
    stage(gAl, LAl, 0); stage(gAl, LAl, 1);
    stage(gBh, LBh, 0); stage(gBh, LBh, 1);
    stage(gBl, LBl, 0); stage(gBl, LBl, 1);
    __syncthreads();

    bf16x8 aH[4], aL[4], bH[4], bL[4];
#pragma unroll
    for (int rb = 0; rb < 4; ++rb) {
      const int off = (wr * 64 + rb * 16 + lr) * 32 + kg * 8;
      aH[rb] = *(const bf16x8*)(LAh + off);
      aL[rb] = *(const bf16x8*)(LAl + off);
    }
#pragma unroll
    for (int cb = 0; cb < 4; ++cb) {
      const int off = (wc * 64 + cb * 16 + lr) * 32 + kg * 8;
      bH[cb] = *(const bf16x8*)(LBh + off);
      bL[cb] = *(const bf16x8*)(LBl + off);
    }
#pragma unroll
    for (int rb = 0; rb < 4; ++rb)
#pragma unroll
      for (int cb = 0; cb < 4; ++cb) {
        acc[rb][cb] = __builtin_amdgcn_mfma_f32_16x16x32_bf16(
            aH[rb], bH[cb], acc[rb][cb], 0, 0, 0);
        acc[rb][cb] = __builtin_amdgcn_mfma_f32_16x16x32_bf16(
            aH[rb], bL[cb], acc[rb][cb], 0, 0, 0);
        acc[rb][cb] = __builtin_amdgcn_mfma_f32_16x16x32_bf16(
            aL[rb], bH[cb], acc[rb][cb], 0, 0, 0);
      }
  }

  // C/D layout: col = lane&15, row = (lane>>4)*4 + reg.
#pragma unroll
  for (int cb = 0; cb < 4; ++cb) {
    const int col = n0 + wc * 64 + cb * 16 + lr;
    const float bv = bias[col];
    if (MODE == 0) {
      const int h = col / 192;
      const int rem = col - h * 192;
      const int dd = rem / 3;
      const int s = rem - dd * 3;
      if (s == 2) {
        // V: 4 consecutive n -> one 8B store into the [64][64] kt tile
#pragma unroll
        for (int rb = 0; rb < 4; ++rb) {
          const int m = m0 + wr * 64 + rb * 16 + kg * 4;
          const int bb = m >> 11, nn = m & (N - 1);
          f16x4 pk;
#pragma unroll
          for (int r = 0; r < 4; ++r)
            pk[r] = (_Float16)(acc[rb][cb][r] + bv);
          const size_t vidx =
              ((((size_t)bb * H + h) * (N / 64) + (nn >> 6)) * 64 + dd) * 64 +
              (nn & 63);
          *(f16x4*)((_Float16*)vt + vidx) = pk;
        }
      } else {
#pragma unroll
        for (int rb = 0; rb < 4; ++rb)
#pragma unroll
          for (int r = 0; r < 4; ++r) {
            const int m = m0 + wr * 64 + rb * 16 + kg * 4 + r;
            const int bb = m >> 11, nn = m & (N - 1);
            float v = acc[rb][cb][r] + bv;
            ushort hi, lo;
            const size_t idx = (((size_t)bb * H + h) * N + nn) * D + dd;
            if (s == 0) {
              v *= 0.125f;  // fold 1/sqrt(D), exact pow2
              split2(v, hi, lo);
              qh[idx] = hi; ql[idx] = lo;
            } else {
              split2(v, hi, lo);
              kh[idx] = hi; kl[idx] = lo;
            }
          }
      }
    } else {
#pragma unroll
      for (int rb = 0; rb < 4; ++rb)
#pragma unroll
        for (int r = 0; r < 4; ++r) {
          const int m = m0 + wr * 64 + rb * 16 + kg * 4 + r;
          outp[(size_t)m * E + col] = acc[rb][cb][r] + bv;
        }
    }
  }
}

// ---------------------------------------------------------------------------
// MFMA flash attention v3: 512 threads = 8 waves x 64 Q-rows (512 rows/block)
// -> only 4 blocks per bh (KV refetch halved vs r4/r5). Grid (bh=64, qt=4),
// bh fastest-varying so the 4 qt blocks of a bh share an XCD.
// KVBLK=64, K/V double-buffered, counted s_waitcnt vmcnt(3) + raw s_barrier
// (3 global_load_lds per thread per tile stay in flight across the barrier).
// QK^T: bf16x3; PV: fp16; P in per-wave swizzled LDS. LDS = 112 KB, 1 blk/CU.
// ---------------------------------------------------------------------------
__global__ __launch_bounds__(512, 2) void attn_mfma(
    const ushort* __restrict__ Qh, const ushort* __restrict__ Ql,
    const ushort* __restrict__ Kh, const ushort* __restrict__ Kl,
    const ushort* __restrict__ Vt, ushort* __restrict__ Aoh,
    ushort* __restrict__ Aol) {
  __shared__ ushort KhL[2][4096], KlL[2][4096], VtL[2][4096], PsL[8][4096];
  const int tid = threadIdx.x;
  const int l = tid & 63, w = tid >> 6;  // 8 waves
  const int lr = l & 15, g = l >> 4;
  const int bh = blockIdx.x, bb = bh >> 4, hh = bh & 15;
  const int q0 = blockIdx.y * 512 + w * 64;

  // Q A-fragments (scale pre-folded): row = lane&15, k = (lane>>4)*8 + e
  bf16x8 qfh[4][2], qfl[4][2];
#pragma unroll
  for (int rb = 0; rb < 4; ++rb)
#pragma unroll
    for (int ks = 0; ks < 2; ++ks) {
      const size_t off =
          ((size_t)bh * N + q0 + rb * 16 + lr) * D + ks * 32 + g * 8;
      qfh[rb][ks] = *(const bf16x8*)(Qh + off);
      qfl[rb][ks] = *(const bf16x8*)(Ql + off);
    }

  f32x4 o[4][4];
  float m_[4][4], l_[4][4];
#pragma unroll
  for (int rb = 0; rb < 4; ++rb)
#pragma unroll
    for (int r = 0; r < 4; ++r) {
      m_[rb][r] = -1e30f;
      l_[rb][r] = 0.f;
      o[rb][r] = (f32x4){0.f, 0.f, 0.f, 0.f};
    }

  ushort* Pw = &PsL[w][0];

  // Stage tile kt into buffer buf: 3 global_load_lds per thread (8KB/tile).
  auto stage = [&](int buf, int kt) {
    const int r = tid >> 3, c = tid & 7;
    const int cc = (c ^ (r & 7)) * 8;  // pre-swizzled source chunk
    const int dst = buf * 4096 + (tid & ~63) * 8;
    const size_t ko = ((size_t)bh * N + kt * 64 + r) * D + cc;
    const size_t vo = (((size_t)bh * (N / 64) + kt) * 64 + r) * 64 + cc;
    __builtin_amdgcn_global_load_lds(
        (__attribute__((address_space(1))) void*)(Kh + ko),
        (__attribute__((address_space(3))) void*)(&KhL[0][0] + dst), 16, 0, 0);
    __builtin_amdgcn_global_load_lds(
        (__attribute__((address_space(1))) void*)(Kl + ko),
        (__attribute__((address_space(3))) void*)(&KlL[0][0] + dst), 16, 0, 0);
    __builtin_amdgcn_global_load_lds(
        (__attribute__((address_space(1))) void*)(Vt + vo),
        (__attribute__((address_space(3))) void*)(&VtL[0][0] + dst), 16, 0, 0);
  };

  constexpr int NT = N / 64;
  stage(0, 0);
  int cur = 0;

  for (int kt = 0; kt < NT; ++kt) {
    if (kt + 1 < NT) {
      stage(cur ^ 1, kt + 1);
      asm volatile("s_waitcnt vmcnt(3)" ::: "memory");  // tile kt landed
    } else {
      asm volatile("s_waitcnt vmcnt(0)" ::: "memory");
    }
    __builtin_amdgcn_s_barrier();

    const ushort* KhC = &KhL[cur][0];
    const ushort* KlC = &KlL[cur][0];
    const ushort* VtC = &VtL[cur][0];

    // S = Q K^T (x3). B-frag: row = cb*16+lr, chunk = (ks*4+g) ^ (lr&7).
    f32x4 s4[4][4];
#pragma unroll
    for (int rb = 0; rb < 4; ++rb)
#pragma unroll
      for (int cb = 0; cb < 4; ++cb) s4[rb][cb] = (f32x4){0.f, 0.f, 0.f, 0.f};
    __builtin_amdgcn_s_setprio(1);
#pragma unroll
    for (int ks = 0; ks < 2; ++ks) {
      bf16x8 kfh[4], kfl[4];
#pragma unroll
      for (int cb = 0; cb < 4; ++cb) {
        const int sl = (cb * 16 + lr) * 8 + ((ks * 4 + g) ^ (lr & 7));
        kfh[cb] = *(const bf16x8*)(KhC + sl * 8);
        kfl[cb] = *(const bf16x8*)(KlC + sl * 8);
      }
#pragma unroll
      for (int rb = 0; rb < 4; ++rb)
#pragma unroll
        for (int cb = 0; cb < 4; ++cb) {
          s4[rb][cb] = __builtin_amdgcn_mfma_f32_16x16x32_bf16(
              qfh[rb][ks], kfh[cb], s4[rb][cb], 0, 0, 0);
          s4[rb][cb] = __builtin_amdgcn_mfma_f32_16x16x32_bf16(
              qfh[rb][ks], kfl[cb], s4[rb][cb], 0, 0, 0);
          s4[rb][cb] = __builtin_amdgcn_mfma_f32_16x16x32_bf16(
              qfl[rb][ks], kfh[cb], s4[rb][cb], 0, 0, 0);
        }
    }
    __builtin_amdgcn_s_setprio(0);

    // Online softmax. Row r_glob = rb*16 + g*4 + reg; 16 lanes (lr) share it.
#pragma unroll
    for (int rb = 0; rb < 4; ++rb)
#pragma unroll
      for (int r = 0; r < 4; ++r) {
        float mx = fmaxf(fmaxf(s4[rb][0][r], s4[rb][1][r]),
                         fmaxf(s4[rb][2][r], s4[rb][3][r]));
        mx = fmaxf(mx, __shfl_xor(mx, 1, 16));
        mx = fmaxf(mx, __shfl_xor(mx, 2, 16));
        mx = fmaxf(mx, __shfl_xor(mx, 4, 16));
        mx = fmaxf(mx, __shfl_xor(mx, 8, 16));
        const float mn = fmaxf(m_[rb][r], mx);
        const float fac = __expf(m_[rb][r] - mn);
        m_[rb][r] = mn;
        float sum = 0.f;
#pragma unroll
        for (int cb = 0; cb < 4; ++cb) {
          const float p = __expf(s4[rb][cb][r] - mn);
          s4[rb][cb][r] = p;
          sum += p;
        }
        sum += __shfl_xor(sum, 1, 16);
        sum += __shfl_xor(sum, 2, 16);
        sum += __shfl_xor(sum, 4, 16);
        sum += __shfl_xor(sum, 8, 16);
        l_[rb][r] = l_[rb][r] * fac + sum;
#pragma unroll
        for (int cb = 0; cb < 4; ++cb) o[rb][cb][r] *= fac;
        // P -> per-wave LDS (fp16), same XOR swizzle as K/V tiles
        const int row = rb * 16 + g * 4 + r;
#pragma unroll
        for (int cb = 0; cb < 4; ++cb) {
          const int idx = (row * 64 + cb * 16 + lr) ^ ((row & 7) << 3);
          ((_Float16*)Pw)[idx] = (_Float16)s4[rb][cb][r];
        }
      }

    // O += P @ V (fp16 MFMA). A-frag P: row = rb*16+lr; B-frag V: row=cb*16+lr.
    __builtin_amdgcn_s_setprio(1);
#pragma unroll
    for (int ks = 0; ks < 2; ++ks) {
      f16x8 pf[4], vf[4];
#pragma unroll
      for (int rb = 0; rb < 4; ++rb) {
        const int sl = (rb * 16 + lr) * 8 + ((ks * 4 + g) ^ (lr & 7));
        pf[rb] = *(const f16x8*)(Pw + sl * 8);
      }
#pragma unroll
      for (int cb = 0; cb < 4; ++cb) {
        const int sl = (cb * 16 + lr) * 8 + ((ks * 4 + g) ^ (lr & 7));
        vf[cb] = *(const f16x8*)(VtC + sl * 8);
      }
#pragma unroll
      for (int rb = 0; rb < 4; ++rb)
#pragma unroll
        for (int cb = 0; cb < 4; ++cb)
          o[rb][cb] = __builtin_amdgcn_mfma_f32_16x16x32_f16(
              pf[rb], vf[cb], o[rb][cb], 0, 0, 0);
    }
    __builtin_amdgcn_s_setprio(0);

    __builtin_amdgcn_s_barrier();  // all waves done with buf[cur]
    cur ^= 1;
  }

  // Epilogue: normalize, split hi/lo, write [b, n, h*D + d]
#pragma unroll
  for (int rb = 0; rb < 4; ++rb)
#pragma unroll
    for (int r = 0; r < 4; ++r) {
      const float inv = 1.f / l_[rb][r];
      const int n = q0 + rb * 16 + g * 4 + r;
      const size_t base = ((size_t)bb * N + n) * E + hh * D;
#pragma unroll
      for (int cb = 0; cb < 4; ++cb) {
        ushort hi, lo;
        split2(o[rb][cb][r] * inv, hi, lo);
        Aoh[base + cb * 16 + lr] = hi;
        Aol[base + cb * 16 + lr] = lo;
      }
    }
}

}  // namespace

extern "C" void kernel_launch(void* const* d_in, const int* in_sizes, int n_in,
                              void* d_out, int out_size, void* d_ws,
                              size_t ws_size, hipStream_t stream) {
  (void)in_sizes; (void)n_in; (void)out_size; (void)ws_size;
  const float* x      = (const float*)d_in[0];
  const float* w_qkv  = (const float*)d_in[1];
  const float* b_qkv  = (const float*)d_in[2];
  const float* w_proj = (const float*)d_in[3];
  const float* b_proj = (const float*)d_in[4];
  float* out = (float*)d_out;

  constexpr size_t MB = 1ull << 20;
  char* w = (char*)d_ws;
  ushort* xh  = (ushort*)(w + 0 * MB);    // 16 MB
  ushort* xl  = (ushort*)(w + 16 * MB);   // 16 MB
  ushort* wqh = (ushort*)(w + 32 * MB);   // 6 MB
  ushort* wql = (ushort*)(w + 38 * MB);   // 6 MB
  ushort* wph = (ushort*)(w + 44 * MB);   // 2 MB
  ushort* wpl = (ushort*)(w + 46 * MB);   // 2 MB
  ushort* Aoh = (ushort*)(w + 48 * MB);   // 16 MB
  ushort* Aol = (ushort*)(w + 64 * MB);   // 16 MB
  ushort* Qh  = (ushort*)(w + 80 * MB);   // 16 MB
  ushort* Ql  = (ushort*)(w + 96 * MB);   // 16 MB
  ushort* Kh  = (ushort*)(w + 112 * MB);  // 16 MB
  ushort* Kl  = (ushort*)(w + 128 * MB);  // 16 MB
  ushort* Vt  = (ushort*)(w + 144 * MB);  // 16 MB (fp16, tile-blocked)

  split_kernel<<<2048, 256, 0, stream>>>(x, xh, xl, (M * E) / 4);
  split_kernel<<<1024, 256, 0, stream>>>(w_qkv, wqh, wql, (3 * E * E) / 4);
  split_kernel<<<512, 256, 0, stream>>>(w_proj, wph, wpl, (E * E) / 4);

  gemm_x3<0><<<dim3(M / 128, 3 * E / 128), 256, 0, stream>>>(
      xh, xl, wqh, wql, b_qkv, Qh, Ql, Kh, Kl, Vt, nullptr);

  attn_mfma<<<dim3(B * H, N / 512), 512, 0, stream>>>(Qh, Ql, Kh, Kl, Vt, Aoh,
                                                      Aol);

  gemm_x3<1><<<dim3(M / 128, E / 128), 256, 0, stream>>>(
      Aoh, Aol, wph, wpl, b_proj, nullptr, nullptr, nullptr, nullptr, nullptr,
      out);
}

// Round 7
// 1057.144 us; speedup vs baseline: 1.1066x; 1.1066x over previous
//
#include <hip/hip_runtime.h>
#include <hip/hip_fp16.h>

namespace {

constexpr int B = 4;
constexpr int N = 2048;
constexpr int E = 1024;
constexpr int H = 16;
constexpr int D = 64;
constexpr int M = B * N;  // 8192

typedef __attribute__((ext_vector_type(8))) short bf16x8;
typedef __attribute__((ext_vector_type(8))) _Float16 f16x8;
typedef __attribute__((ext_vector_type(4))) _Float16 f16x4;
typedef __attribute__((ext_vector_type(4))) float f32x4;

__device__ inline ushort bf16_rne(float f) {
  unsigned u = __float_as_uint(f);
  return (ushort)((u + 0x7FFFu + ((u >> 16) & 1u)) >> 16);
}
// fp32 -> hi (truncated bf16) + lo (rne bf16 of remainder); hi+lo ~ 17-bit mantissa
__device__ inline void split2(float f, ushort& hi, ushort& lo) {
  unsigned u = __float_as_uint(f);
  hi = (ushort)(u >> 16);
  lo = bf16_rne(f - __uint_as_float(u & 0xFFFF0000u));
}

// ---------------------------------------------------------------------------
// Elementwise fp32 -> (hi, lo) bf16 split
// ---------------------------------------------------------------------------
__global__ __launch_bounds__(256) void split_kernel(
    const float* __restrict__ in, ushort* __restrict__ hi,
    ushort* __restrict__ lo, int n4) {
  int i = blockIdx.x * blockDim.x + threadIdx.x;
  const int stride = gridDim.x * blockDim.x;
  for (; i < n4; i += stride) {
    const float4 f = ((const float4*)in)[i];
    ushort4 h, l;
    split2(f.x, h.x, l.x);
    split2(f.y, h.y, l.y);
    split2(f.z, h.z, l.z);
    split2(f.w, h.w, l.w);
    ((ushort4*)hi)[i] = h;
    ((ushort4*)lo)[i] = l;
  }
}

// ---------------------------------------------------------------------------
// bf16x3 MFMA GEMM. Tile 128x128, BK=32, 4 waves.
// MODE 0 epilogue: col = h*192 + d*3 + s ->
//   s==0: Q *(1/8) split -> Qh/Ql  [B,H,N,D] bf16
//   s==1: K split        -> Kh/Kl  [B,H,N,D] bf16
//   s==2: V -> Vtb [B,H,kt=N/64][d=64][64] fp16 tile-blocked transpose
// MODE 1 epilogue: out[m][col] = acc + bias (fp32)
// ---------------------------------------------------------------------------
template <int MODE>
__global__ __launch_bounds__(256) void gemm_x3(
    const ushort* __restrict__ Ahg, const ushort* __restrict__ Alg,
    const ushort* __restrict__ Bhg, const ushort* __restrict__ Blg,
    const float* __restrict__ bias, ushort* __restrict__ qh,
    ushort* __restrict__ ql, ushort* __restrict__ kh, ushort* __restrict__ kl,
    ushort* __restrict__ vt, float* __restrict__ outp) {
  __shared__ ushort LAh[4096], LAl[4096], LBh[4096], LBl[4096];
  const int tid = threadIdx.x;
  const int l = tid & 63, wid = tid >> 6;
  const int wr = wid >> 1, wc = wid & 1;
  const int lr = l & 15, kg = l >> 4;
  const int m0 = blockIdx.x * 128, n0 = blockIdx.y * 128;

  f32x4 acc[4][4];
#pragma unroll
  for (int i = 0; i < 4; ++i)
#pragma unroll
    for (int j = 0; j < 4; ++j) acc[i][j] = (f32x4){0.f, 0.f, 0.f, 0.f};

  for (int k0 = 0; k0 < E; k0 += 32) {
    const ushort* gAh = Ahg + (size_t)m0 * E + k0;
    const ushort* gAl = Alg + (size_t)m0 * E + k0;
    const ushort* gBh = Bhg + (size_t)n0 * E + k0;
    const ushort* gBl = Blg + (size_t)n0 * E + k0;
    __syncthreads();
    auto stage = [&](const ushort* gp, ushort* lp, int half) {
      const int c = half * 256 + tid;
      __builtin_amdgcn_global_load_lds(
          (__attribute__((address_space(1))) void*)(gp + (size_t)(c >> 2) * E +
                                                    (c & 3) * 8),
          (__attribute__((address_space(3))) void*)(lp +
                                                    (half * 256 + (tid & ~63)) * 8),
          16, 0, 0);
    };
    stage(gAh, LAh, 0); stage(gAh, LAh, 1);
    stage(gAl, LAl, 0); stage(gAl, LAl, 1);
    stage(gBh, LBh, 0); stage(gBh, LBh, 1);
    stage(gBl, LBl, 0); stage(gBl, LBl, 1);
    __syncthreads();

    bf16x8 aH[4], aL[4], bH[4], bL[4];
#pragma unroll
    for (int rb = 0; rb < 4; ++rb) {
      const int off = (wr * 64 + rb * 16 + lr) * 32 + kg * 8;
      aH[rb] = *(const bf16x8*)(LAh + off);
      aL[rb] = *(const bf16x8*)(LAl + off);
    }
#pragma unroll
    for (int cb = 0; cb < 4; ++cb) {
      const int off = (wc * 64 + cb * 16 + lr) * 32 + kg * 8;
      bH[cb] = *(const bf16x8*)(LBh + off);
      bL[cb] = *(const bf16x8*)(LBl + off);
    }
#pragma unroll
    for (int rb = 0; rb < 4; ++rb)
#pragma unroll
      for (int cb = 0; cb < 4; ++cb) {
        acc[rb][cb] = __builtin_amdgcn_mfma_f32_16x16x32_bf16(
            aH[rb], bH[cb], acc[rb][cb], 0, 0, 0);
        acc[rb][cb] = __builtin_amdgcn_mfma_f32_16x16x32_bf16(
            aH[rb], bL[cb], acc[rb][cb], 0, 0, 0);
        acc[rb][cb] = __builtin_amdgcn_mfma_f32_16x16x32_bf16(
            aL[rb], bH[cb], acc[rb][cb], 0, 0, 0);
      }
  }

  // C/D layout: col = lane&15, row = (lane>>4)*4 + reg.
#pragma unroll
  for (int cb = 0; cb < 4; ++cb) {
    const int col = n0 + wc * 64 + cb * 16 + lr;
    const float bv = bias[col];
    if (MODE == 0) {
      const int h = col / 192;
      const int rem = col - h * 192;
      const int dd = rem / 3;
      const int s = rem - dd * 3;
      if (s == 2) {
        // V: 4 consecutive n -> one 8B store into the [64][64] kt tile
#pragma unroll
        for (int rb = 0; rb < 4; ++rb) {
          const int m = m0 + wr * 64 + rb * 16 + kg * 4;
          const int bb = m >> 11, nn = m & (N - 1);
          f16x4 pk;
#pragma unroll
          for (int r = 0; r < 4; ++r)
            pk[r] = (_Float16)(acc[rb][cb][r] + bv);
          const size_t vidx =
              ((((size_t)bb * H + h) * (N / 64) + (nn >> 6)) * 64 + dd) * 64 +
              (nn & 63);
          *(f16x4*)((_Float16*)vt + vidx) = pk;
        }
      } else {
#pragma unroll
        for (int rb = 0; rb < 4; ++rb)
#pragma unroll
          for (int r = 0; r < 4; ++r) {
            const int m = m0 + wr * 64 + rb * 16 + kg * 4 + r;
            const int bb = m >> 11, nn = m & (N - 1);
            float v = acc[rb][cb][r] + bv;
            ushort hi, lo;
            const size_t idx = (((size_t)bb * H + h) * N + nn) * D + dd;
            if (s == 0) {
              v *= 0.125f;  // fold 1/sqrt(D), exact pow2
              split2(v, hi, lo);
              qh[idx] = hi; ql[idx] = lo;
            } else {
              split2(v, hi, lo);
              kh[idx] = hi; kl[idx] = lo;
            }
          }
      }
    } else {
#pragma unroll
      for (int rb = 0; rb < 4; ++rb)
#pragma unroll
        for (int r = 0; r < 4; ++r) {
          const int m = m0 + wr * 64 + rb * 16 + kg * 4 + r;
          outp[(size_t)m * E + col] = acc[rb][cb][r] + bv;
        }
    }
  }
}

// ---------------------------------------------------------------------------
// MFMA flash attention v4: REGISTER-STAGED K/V (plain global_load_dwordx4 ->
// VGPR -> swizzled ds_write_b128) instead of global_load_lds, which showed
// 4.1x HBM fetch amplification (941 MB vs 230 MB demand). Global reads are
// now linear/coalesced; the XOR swizzle is applied on the LDS write address.
// 256 thr = 4 waves x 64 Q-rows; grid (bh=64, qt=8): linear id = bh + 64*qt
// -> XCD = bh%8, so all 8 qt blocks of a bh co-reside on one XCD.
// K/V double-buffered; loads for kt+1 in flight across compute (raw
// s_barrier + explicit vmcnt/lgkmcnt); kt loop unrolled x2 so the two
// staging register sets are statically named. LDS 80 KB -> 2 blocks/CU.
// QK^T: bf16x3; PV: fp16; P in per-wave swizzled LDS buffer.
// ---------------------------------------------------------------------------
__global__ __launch_bounds__(256, 2) void attn_mfma(
    const ushort* __restrict__ Qh, const ushort* __restrict__ Ql,
    const ushort* __restrict__ Kh, const ushort* __restrict__ Kl,
    const ushort* __restrict__ Vt, ushort* __restrict__ Aoh,
    ushort* __restrict__ Aol) {
  __shared__ ushort KhL[2][4096], KlL[2][4096], VtL[2][4096], PsL[4][4096];
  const int tid = threadIdx.x;
  const int l = tid & 63, w = tid >> 6;
  const int lr = l & 15, g = l >> 4;
  const int bh = blockIdx.x, bb = bh >> 4, hh = bh & 15;
  const int q0 = blockIdx.y * 256 + w * 64;

  // Staging descriptors: thread covers row sr (0..63), chunks sc and sc+4
  // (16B chunks of the 128B row). Global reads linear; LDS slot XOR-swizzled.
  const int sr = tid >> 2;       // 0..63
  const int sc = tid & 3;        // 0..3
  const int slotA = sr * 8 + (sc ^ (sr & 7));
  const int slotB = sr * 8 + ((sc + 4) ^ (sr & 7));

  // Q A-fragments (scale pre-folded): row = lane&15, k = (lane>>4)*8 + e
  bf16x8 qfh[4][2], qfl[4][2];
#pragma unroll
  for (int rb = 0; rb < 4; ++rb)
#pragma unroll
    for (int ks = 0; ks < 2; ++ks) {
      const size_t off =
          ((size_t)bh * N + q0 + rb * 16 + lr) * D + ks * 32 + g * 8;
      qfh[rb][ks] = *(const bf16x8*)(Qh + off);
      qfl[rb][ks] = *(const bf16x8*)(Ql + off);
    }

  f32x4 o[4][4];
  float m_[4][4], l_[4][4];
#pragma unroll
  for (int rb = 0; rb < 4; ++rb)
#pragma unroll
    for (int r = 0; r < 4; ++r) {
      m_[rb][r] = -1e30f;
      l_[rb][r] = 0.f;
      o[rb][r] = (f32x4){0.f, 0.f, 0.f, 0.f};
    }

  ushort* Pw = &PsL[w][0];
  constexpr int NT = N / 64;

#define LOAD_SET(SET, KT)                                                     \
  do {                                                                        \
    const size_t ko = ((size_t)bh * N + (size_t)(KT) * 64 + sr) * 64;         \
    const size_t vo = (((size_t)bh * (N / 64) + (KT)) * 64 + sr) * 64;        \
    SET[0] = *(const uint4*)(Kh + ko + sc * 8);                               \
    SET[1] = *(const uint4*)(Kh + ko + (sc + 4) * 8);                         \
    SET[2] = *(const uint4*)(Kl + ko + sc * 8);                               \
    SET[3] = *(const uint4*)(Kl + ko + (sc + 4) * 8);                         \
    SET[4] = *(const uint4*)(Vt + vo + sc * 8);                               \
    SET[5] = *(const uint4*)(Vt + vo + (sc + 4) * 8);                         \
  } while (0)

#define WRITE_SET(SET, BUF)                                                   \
  do {                                                                        \
    *(uint4*)(&KhL[BUF][slotA * 8]) = SET[0];                                 \
    *(uint4*)(&KhL[BUF][slotB * 8]) = SET[1];                                 \
    *(uint4*)(&KlL[BUF][slotA * 8]) = SET[2];                                 \
    *(uint4*)(&KlL[BUF][slotB * 8]) = SET[3];                                 \
    *(uint4*)(&VtL[BUF][slotA * 8]) = SET[4];                                 \
    *(uint4*)(&VtL[BUF][slotB * 8]) = SET[5];                                 \
  } while (0)

  auto compute = [&](int buf) {
    const ushort* KhC = &KhL[buf][0];
    const ushort* KlC = &KlL[buf][0];
    const ushort* VtC = &VtL[buf][0];

    // S = Q K^T (x3). B-frag: row = cb*16+lr, chunk = (ks*4+g) ^ (lr&7).
    f32x4 s4[4][4];
#pragma unroll
    for (int rb = 0; rb < 4; ++rb)
#pragma unroll
      for (int cb = 0; cb < 4; ++cb) s4[rb][cb] = (f32x4){0.f, 0.f, 0.f, 0.f};
    __builtin_amdgcn_s_setprio(1);
#pragma unroll
    for (int ks = 0; ks < 2; ++ks) {
      bf16x8 kfh[4], kfl[4];
#pragma unroll
      for (int cb = 0; cb < 4; ++cb) {
        const int sl = (cb * 16 + lr) * 8 + ((ks * 4 + g) ^ (lr & 7));
        kfh[cb] = *(const bf16x8*)(KhC + sl * 8);
        kfl[cb] = *(const bf16x8*)(KlC + sl * 8);
      }
#pragma unroll
      for (int rb = 0; rb < 4; ++rb)
#pragma unroll
        for (int cb = 0; cb < 4; ++cb) {
          s4[rb][cb] = __builtin_amdgcn_mfma_f32_16x16x32_bf16(
              qfh[rb][ks], kfh[cb], s4[rb][cb], 0, 0, 0);
          s4[rb][cb] = __builtin_amdgcn_mfma_f32_16x16x32_bf16(
              qfh[rb][ks], kfl[cb], s4[rb][cb], 0, 0, 0);
          s4[rb][cb] = __builtin_amdgcn_mfma_f32_16x16x32_bf16(
              qfl[rb][ks], kfh[cb], s4[rb][cb], 0, 0, 0);
        }
    }
    __builtin_amdgcn_s_setprio(0);

    // Online softmax. Row r_glob = rb*16 + g*4 + reg; 16 lanes (lr) share it.
#pragma unroll
    for (int rb = 0; rb < 4; ++rb)
#pragma unroll
      for (int r = 0; r < 4; ++r) {
        float mx = fmaxf(fmaxf(s4[rb][0][r], s4[rb][1][r]),
                         fmaxf(s4[rb][2][r], s4[rb][3][r]));
        mx = fmaxf(mx, __shfl_xor(mx, 1, 16));
        mx = fmaxf(mx, __shfl_xor(mx, 2, 16));
        mx = fmaxf(mx, __shfl_xor(mx, 4, 16));
        mx = fmaxf(mx, __shfl_xor(mx, 8, 16));
        const float mn = fmaxf(m_[rb][r], mx);
        const float fac = __expf(m_[rb][r] - mn);
        m_[rb][r] = mn;
        float sum = 0.f;
#pragma unroll
        for (int cb = 0; cb < 4; ++cb) {
          const float p = __expf(s4[rb][cb][r] - mn);
          s4[rb][cb][r] = p;
          sum += p;
        }
        sum += __shfl_xor(sum, 1, 16);
        sum += __shfl_xor(sum, 2, 16);
        sum += __shfl_xor(sum, 4, 16);
        sum += __shfl_xor(sum, 8, 16);
        l_[rb][r] = l_[rb][r] * fac + sum;
#pragma unroll
        for (int cb = 0; cb < 4; ++cb) o[rb][cb][r] *= fac;
        const int row = rb * 16 + g * 4 + r;
#pragma unroll
        for (int cb = 0; cb < 4; ++cb) {
          const int idx = (row * 64 + cb * 16 + lr) ^ ((row & 7) << 3);
          ((_Float16*)Pw)[idx] = (_Float16)s4[rb][cb][r];
        }
      }

    // O += P @ V (fp16 MFMA)
    __builtin_amdgcn_s_setprio(1);
#pragma unroll
    for (int ks = 0; ks < 2; ++ks) {
      f16x8 pf[4], vf[4];
#pragma unroll
      for (int rb = 0; rb < 4; ++rb) {
        const int sl = (rb * 16 + lr) * 8 + ((ks * 4 + g) ^ (lr & 7));
        pf[rb] = *(const f16x8*)(Pw + sl * 8);
      }
#pragma unroll
      for (int cb = 0; cb < 4; ++cb) {
        const int sl = (cb * 16 + lr) * 8 + ((ks * 4 + g) ^ (lr & 7));
        vf[cb] = *(const f16x8*)(VtC + sl * 8);
      }
#pragma unroll
      for (int rb = 0; rb < 4; ++rb)
#pragma unroll
        for (int cb = 0; cb < 4; ++cb)
          o[rb][cb] = __builtin_amdgcn_mfma_f32_16x16x32_f16(
              pf[rb], vf[cb], o[rb][cb], 0, 0, 0);
    }
    __builtin_amdgcn_s_setprio(0);
  };

  uint4 sA[6], sB[6];
  LOAD_SET(sA, 0);

  for (int kt2 = 0; kt2 < NT; kt2 += 2) {
    // ---- tile kt2 (buffer 0, regs sA; prefetch kt2+1 into sB) ----
    asm volatile("s_waitcnt vmcnt(0)" ::: "memory");
    __builtin_amdgcn_s_barrier();  // all waves done reading buf 0
    WRITE_SET(sA, 0);
    if (kt2 + 1 < NT) LOAD_SET(sB, kt2 + 1);
    asm volatile("s_waitcnt lgkmcnt(0)" ::: "memory");
    __builtin_amdgcn_s_barrier();  // buf 0 ready
    compute(0);
    // ---- tile kt2+1 (buffer 1, regs sB; prefetch kt2+2 into sA) ----
    asm volatile("s_waitcnt vmcnt(0)" ::: "memory");
    __builtin_amdgcn_s_barrier();  // all waves done reading buf 1
    WRITE_SET(sB, 1);
    if (kt2 + 2 < NT) LOAD_SET(sA, kt2 + 2);
    asm volatile("s_waitcnt lgkmcnt(0)" ::: "memory");
    __builtin_amdgcn_s_barrier();  // buf 1 ready
    compute(1);
  }
#undef LOAD_SET
#undef WRITE_SET

  // Epilogue: normalize, split hi/lo, write [b, n, h*D + d]
#pragma unroll
  for (int rb = 0; rb < 4; ++rb)
#pragma unroll
    for (int r = 0; r < 4; ++r) {
      const float inv = 1.f / l_[rb][r];
      const int n = q0 + rb * 16 + g * 4 + r;
      const size_t base = ((size_t)bb * N + n) * E + hh * D;
#pragma unroll
      for (int cb = 0; cb < 4; ++cb) {
        ushort hi, lo;
        split2(o[rb][cb][r] * inv, hi, lo);
        Aoh[base + cb * 16 + lr] = hi;
        Aol[base + cb * 16 + lr] = lo;
      }
    }
}

}  // namespace

extern "C" void kernel_launch(void* const* d_in, const int* in_sizes, int n_in,
                              void* d_out, int out_size, void* d_ws,
                              size_t ws_size, hipStream_t stream) {
  (void)in_sizes; (void)n_in; (void)out_size; (void)ws_size;
  const float* x      = (const float*)d_in[0];
  const float* w_qkv  = (const float*)d_in[1];
  const float* b_qkv  = (const float*)d_in[2];
  const float* w_proj = (const float*)d_in[3];
  const float* b_proj = (const float*)d_in[4];
  float* out = (float*)d_out;

  constexpr size_t MB = 1ull << 20;
  char* w = (char*)d_ws;
  ushort* xh  = (ushort*)(w + 0 * MB);    // 16 MB
  ushort* xl  = (ushort*)(w + 16 * MB);   // 16 MB
  ushort* wqh = (ushort*)(w + 32 * MB);   // 6 MB
  ushort* wql = (ushort*)(w + 38 * MB);   // 6 MB
  ushort* wph = (ushort*)(w + 44 * MB);   // 2 MB
  ushort* wpl = (ushort*)(w + 46 * MB);   // 2 MB
  ushort* Aoh = (ushort*)(w + 48 * MB);   // 16 MB
  ushort* Aol = (ushort*)(w + 64 * MB);   // 16 MB
  ushort* Qh  = (ushort*)(w + 80 * MB);   // 16 MB
  ushort* Ql  = (ushort*)(w + 96 * MB);   // 16 MB
  ushort* Kh  = (ushort*)(w + 112 * MB);  // 16 MB
  ushort* Kl  = (ushort*)(w + 128 * MB);  // 16 MB
  ushort* Vt  = (ushort*)(w + 144 * MB);  // 16 MB (fp16, tile-blocked)

  split_kernel<<<2048, 256, 0, stream>>>(x, xh, xl, (M * E) / 4);
  split_kernel<<<1024, 256, 0, stream>>>(w_qkv, wqh, wql, (3 * E * E) / 4);
  split_kernel<<<512, 256, 0, stream>>>(w_proj, wph, wpl, (E * E) / 4);

  gemm_x3<0><<<dim3(M / 128, 3 * E / 128), 256, 0, stream>>>(
      xh, xl, wqh, wql, b_qkv, Qh, Ql, Kh, Kl, Vt, nullptr);

  attn_mfma<<<dim3(B * H, N / 256), 256, 0, stream>>>(Qh, Ql, Kh, Kl, Vt, Aoh,
                                                      Aol);

  gemm_x3<1><<<dim3(M / 128, E / 128), 256, 0, stream>>>(
      Aoh, Aol, wph, wpl, b_proj, nullptr, nullptr, nullptr, nullptr, nullptr,
      out);
}